// Round 1
// baseline (1810.509 us; speedup 1.0000x reference)
//
#include <hip/hip_runtime.h>
#include <math.h>

#define BB 32
#define NN 8192
#define DD 512
#define NSLOT 8
#define NITER 3
#define EPSF 1e-8f
#define LNEPS 1e-5f
#define SCALE 0.04419417382415922f   // 1/sqrt(512)

// ---------------------------------------------------------------------------
// slots = mu + exp(logsigma) * noise   (broadcast [1,1,D] over [B,NS,D])
__global__ __launch_bounds__(256) void k_init(const float* __restrict__ noise,
                                              const float* __restrict__ mu,
                                              const float* __restrict__ lsig,
                                              float* __restrict__ slots) {
    int t = blockIdx.x * blockDim.x + threadIdx.x;   // 0 .. B*NS*D-1
    int d = t & (DD - 1);
    slots[t] = fmaf(__expf(lsig[d]), noise[t], mu[d]);
}

// ---------------------------------------------------------------------------
// s = layernorm(slots, w, b); s_sq = sum(s*s).  One wave per (b,slot) row.
__global__ __launch_bounds__(64) void k_prep(const float* __restrict__ slots,
                                             const float* __restrict__ w,
                                             const float* __restrict__ bias,
                                             float* __restrict__ s,
                                             float* __restrict__ s_sq) {
    int row  = blockIdx.x;          // b*NSLOT + i
    int lane = threadIdx.x;
    int d0   = lane * 4;
    const float* p = slots + (size_t)row * DD;
    float4 va = *(const float4*)(p + d0);
    float4 vb = *(const float4*)(p + 256 + d0);
    float v[8] = {va.x, va.y, va.z, va.w, vb.x, vb.y, vb.z, vb.w};
    float sum = 0.f, sq = 0.f;
#pragma unroll
    for (int k = 0; k < 8; ++k) { sum += v[k]; sq = fmaf(v[k], v[k], sq); }
#pragma unroll
    for (int off = 32; off; off >>= 1) {
        sum += __shfl_xor(sum, off);
        sq  += __shfl_xor(sq,  off);
    }
    float m   = sum * (1.f / DD);
    float var = fmaf(-m, m, sq * (1.f / DD));
    float rs  = rsqrtf(var + LNEPS);
    float murs = m * rs;

    float4 w0 = *(const float4*)(w + d0);
    float4 w1 = *(const float4*)(w + 256 + d0);
    float4 b0 = *(const float4*)(bias + d0);
    float4 b1 = *(const float4*)(bias + 256 + d0);
    float wv[8] = {w0.x, w0.y, w0.z, w0.w, w1.x, w1.y, w1.z, w1.w};
    float bv[8] = {b0.x, b0.y, b0.z, b0.w, b1.x, b1.y, b1.z, b1.w};

    float xs[8]; float ssum = 0.f;
#pragma unroll
    for (int k = 0; k < 8; ++k) {
        xs[k] = fmaf(fmaf(v[k], rs, -murs), wv[k], bv[k]);
        ssum  = fmaf(xs[k], xs[k], ssum);
    }
#pragma unroll
    for (int off = 32; off; off >>= 1) ssum += __shfl_xor(ssum, off);

    float* so = s + (size_t)row * DD;
    *(float4*)(so + d0)       = make_float4(xs[0], xs[1], xs[2], xs[3]);
    *(float4*)(so + 256 + d0) = make_float4(xs[4], xs[5], xs[6], xs[7]);
    if (lane == 0) s_sq[row] = ssum;
}

// ---------------------------------------------------------------------------
// Main fused pass: per row j of inputs -> LN -> dots vs 8 slots -> softmax
// over slots -> accumulate acc_i[d] += p_i*x_d, den_i += p_i.
#define CHUNKS 64                     // blocks per batch
#define ROWSPB (NN / CHUNKS)          // 128 rows per block

__global__ __launch_bounds__(256, 2) void k_main(const float* __restrict__ in,
                                                 const float* __restrict__ lnw,
                                                 const float* __restrict__ lnb,
                                                 const float* __restrict__ s,
                                                 const float* __restrict__ s_sq,
                                                 float* __restrict__ acc,
                                                 float* __restrict__ den) {
    const int b     = blockIdx.x / CHUNKS;
    const int chunk = blockIdx.x % CHUNKS;
    const int wave  = threadIdx.x >> 6;
    const int lane  = threadIdx.x & 63;
    const int d0    = lane * 4;

    __shared__ float s_acc[NSLOT][DD];
    __shared__ float s_den[NSLOT];
    for (int t = threadIdx.x; t < NSLOT * DD; t += 256) ((float*)s_acc)[t] = 0.f;
    if (threadIdx.x < NSLOT) s_den[threadIdx.x] = 0.f;
    __syncthreads();

    // LN weight fragments for this lane's d positions
    float4 w0 = *(const float4*)(lnw + d0);
    float4 w1 = *(const float4*)(lnw + 256 + d0);
    float4 b0 = *(const float4*)(lnb + d0);
    float4 b1 = *(const float4*)(lnb + 256 + d0);
    float wv[8] = {w0.x, w0.y, w0.z, w0.w, w1.x, w1.y, w1.z, w1.w};
    float bv[8] = {b0.x, b0.y, b0.z, b0.w, b1.x, b1.y, b1.z, b1.w};

    // slot fragments in registers: sf[i][k] = s[b,i, lane's k-th d]
    float sf[NSLOT][8];
#pragma unroll
    for (int i = 0; i < NSLOT; ++i) {
        const float* sp = s + ((size_t)(b * NSLOT + i)) * DD;
        float4 A  = *(const float4*)(sp + d0);
        float4 Bv = *(const float4*)(sp + 256 + d0);
        sf[i][0] = A.x;  sf[i][1] = A.y;  sf[i][2] = A.z;  sf[i][3] = A.w;
        sf[i][4] = Bv.x; sf[i][5] = Bv.y; sf[i][6] = Bv.z; sf[i][7] = Bv.w;
    }
    float ssq[NSLOT];
#pragma unroll
    for (int i = 0; i < NSLOT; ++i) ssq[i] = s_sq[b * NSLOT + i];

    float accr[NSLOT][8];
#pragma unroll
    for (int i = 0; i < NSLOT; ++i)
#pragma unroll
        for (int k = 0; k < 8; ++k) accr[i][k] = 0.f;
    float denr[NSLOT];
#pragma unroll
    for (int i = 0; i < NSLOT; ++i) denr[i] = 0.f;

    const int jbase = chunk * ROWSPB;
    for (int jj = wave; jj < ROWSPB; jj += 4) {
        const float* row = in + ((size_t)b * NN + (jbase + jj)) * DD;
        float4 va = *(const float4*)(row + d0);
        float4 vb = *(const float4*)(row + 256 + d0);
        float v[8] = {va.x, va.y, va.z, va.w, vb.x, vb.y, vb.z, vb.w};

        float sum = 0.f, sq = 0.f;
#pragma unroll
        for (int k = 0; k < 8; ++k) { sum += v[k]; sq = fmaf(v[k], v[k], sq); }
#pragma unroll
        for (int off = 32; off; off >>= 1) {
            sum += __shfl_xor(sum, off);
            sq  += __shfl_xor(sq,  off);
        }
        float m_   = sum * (1.f / DD);
        float var  = fmaf(-m_, m_, sq * (1.f / DD));
        float rs   = rsqrtf(var + LNEPS);
        float murs = m_ * rs;

        float x[8];
#pragma unroll
        for (int k = 0; k < 8; ++k)
            x[k] = fmaf(fmaf(v[k], rs, -murs), wv[k], bv[k]);

        float dot[NSLOT];
        float xsq = 0.f;
#pragma unroll
        for (int i = 0; i < NSLOT; ++i) dot[i] = 0.f;
#pragma unroll
        for (int k = 0; k < 8; ++k) {
            xsq = fmaf(x[k], x[k], xsq);
#pragma unroll
            for (int i = 0; i < NSLOT; ++i) dot[i] = fmaf(x[k], sf[i][k], dot[i]);
        }
#pragma unroll
        for (int off = 32; off; off >>= 1) {
            xsq += __shfl_xor(xsq, off);
#pragma unroll
            for (int i = 0; i < NSLOT; ++i) dot[i] += __shfl_xor(dot[i], off);
        }

        // logits over slots, relu (squared distance >= 0), scale, softmax(axis=slots)
        float l[NSLOT];
        float mmax = 0.f;
#pragma unroll
        for (int i = 0; i < NSLOT; ++i) {
            float dist = fmaf(-2.f, dot[i], ssq[i] + xsq);
            l[i] = fmaxf(dist, 0.f) * SCALE;
            mmax = fmaxf(mmax, l[i]);
        }
        float e[NSLOT], se = 0.f;
#pragma unroll
        for (int i = 0; i < NSLOT; ++i) { e[i] = __expf(l[i] - mmax); se += e[i]; }
        float inv = __builtin_amdgcn_rcpf(se);
#pragma unroll
        for (int i = 0; i < NSLOT; ++i) {
            float p = fmaf(e[i], inv, EPSF);
            denr[i] += p;
#pragma unroll
            for (int k = 0; k < 8; ++k) accr[i][k] = fmaf(p, x[k], accr[i][k]);
        }
    }

    // combine waves in LDS
#pragma unroll
    for (int i = 0; i < NSLOT; ++i) {
#pragma unroll
        for (int k = 0; k < 8; ++k) {
            int dpos = (k < 4) ? (d0 + k) : (256 + d0 + k - 4);
            atomicAdd(&s_acc[i][dpos], accr[i][k]);
        }
        if (lane == (int)(i & 63)) { }  // no-op
    }
    if (lane < NSLOT) atomicAdd(&s_den[lane], denr[lane]);
    __syncthreads();

    // one atomic set per block to global
    for (int t = threadIdx.x; t < NSLOT * DD; t += 256)
        atomicAdd(&acc[(size_t)b * NSLOT * DD + t], ((float*)s_acc)[t]);
    if (threadIdx.x < NSLOT)
        atomicAdd(&den[b * NSLOT + threadIdx.x], s_den[threadIdx.x]);
}

// ---------------------------------------------------------------------------
__global__ __launch_bounds__(256) void k_final(const float* __restrict__ acc,
                                               const float* __restrict__ den,
                                               float* __restrict__ out) {
    int t = blockIdx.x * blockDim.x + threadIdx.x;
    out[t] = acc[t] / den[t >> 9];   // DD = 512
}

// ---------------------------------------------------------------------------
extern "C" void kernel_launch(void* const* d_in, const int* in_sizes, int n_in,
                              void* d_out, int out_size, void* d_ws, size_t ws_size,
                              hipStream_t stream) {
    const float* inputs = (const float*)d_in[0];
    const float* noise  = (const float*)d_in[1];
    const float* smu    = (const float*)d_in[2];
    const float* slsig  = (const float*)d_in[3];
    const float* lnw_in = (const float*)d_in[4];
    const float* lnb_in = (const float*)d_in[5];
    const float* lnw_s  = (const float*)d_in[6];
    const float* lnb_s  = (const float*)d_in[7];
    float* out = (float*)d_out;

    float* ws    = (float*)d_ws;
    float* slots = ws;                 // 131072
    float* s     = ws + 131072;        // 131072
    float* ssq   = ws + 262144;        // 256
    float* acc   = ws + 262400;        // 131072
    float* den   = ws + 393472;        // 256

    k_init<<<512, 256, 0, stream>>>(noise, smu, slsig, slots);
    for (int it = 0; it < NITER; ++it) {
        k_prep<<<BB * NSLOT, 64, 0, stream>>>(slots, lnw_s, lnb_s, s, ssq);
        hipMemsetAsync(acc, 0, (NSLOT * DD * BB / BB * BB + 256) * 0 + (131072 + 256) * sizeof(float), stream);
        k_main<<<BB * CHUNKS, 256, 0, stream>>>(inputs, lnw_in, lnb_in, s, ssq, acc, den);
        float* dst = (it == NITER - 1) ? out : slots;
        k_final<<<512, 256, 0, stream>>>(acc, den, dst);
    }
}